// Round 6
// baseline (2907.826 us; speedup 1.0000x reference)
//
#include <hip/hip_runtime.h>
#include <hip/hip_bf16.h>

typedef __hip_bfloat16 bf16;
typedef __bf16 bf16r;
typedef bf16r bf16x8 __attribute__((ext_vector_type(8)));
typedef float f32x4 __attribute__((ext_vector_type(4)));

#define T_SEQ 4096
#define C_DIM 1024
#define LD_QKV 3072
#define MB(x) ((size_t)(x) << 20)

static __device__ __forceinline__ unsigned short f2bf(float f) {
    bf16 h = (bf16)f;
    return *reinterpret_cast<unsigned short*>(&h);
}

// ---------------------------------------------------------------------------
// f32 -> bf16 weight convert, contiguous slice (element offset eoff, n4 vec4s)
// ---------------------------------------------------------------------------
__global__ __launch_bounds__(256) void cvt_w(const float* __restrict__ src, size_t eoff,
                                             ushort4* __restrict__ dst, int n4) {
    int i = blockIdx.x * 256 + threadIdx.x;
    const int stride = gridDim.x * 256;
    const float4* s = (const float4*)(src + eoff);
    for (; i < n4; i += stride) {
        float4 v = s[i];
        ushort4 o;
        o.x = f2bf(v.x); o.y = f2bf(v.y); o.z = f2bf(v.z); o.w = f2bf(v.w);
        dst[i] = o;
    }
}

// ---------------------------------------------------------------------------
// w2 column-slice convert: src f32 [1024][4096], cols [coff, coff+2048)
// -> dst bf16 [1024][2048] (compacted, ld = 2048).  524288 vec4s.
// ---------------------------------------------------------------------------
__global__ __launch_bounds__(256) void cvt_w2h(const float* __restrict__ src, int coff,
                                               ushort4* __restrict__ dst) {
    const int i = blockIdx.x * 256 + threadIdx.x;  // [0, 1024*2048/4)
    const int row = i >> 9;        // 512 vec4 per 2048-col row
    const int c4 = i & 511;
    float4 v = *(const float4*)(src + (size_t)row * 4096 + coff + c4 * 4);
    ushort4 o;
    o.x = f2bf(v.x); o.y = f2bf(v.y); o.z = f2bf(v.z); o.w = f2bf(v.w);
    dst[i] = o;
}

// ---------------------------------------------------------------------------
// RMSNorm: f32 in, f32 weight, bf16 out. One block per row of 1024.
// ---------------------------------------------------------------------------
__global__ __launch_bounds__(256) void rmsnorm_k(const float* __restrict__ x,
                                                 const float* __restrict__ w,
                                                 bf16* __restrict__ out) {
    const int row = blockIdx.x;
    const int tid = threadIdx.x;
    const float* xr = x + (size_t)row * C_DIM;
    float v[4];
    float ss = 0.f;
#pragma unroll
    for (int i = 0; i < 4; i++) { v[i] = xr[tid * 4 + i]; ss += v[i] * v[i]; }
#pragma unroll
    for (int off = 32; off; off >>= 1) ss += __shfl_xor(ss, off);
    __shared__ float red[4];
    if ((tid & 63) == 0) red[tid >> 6] = ss;
    __syncthreads();
    const float tot = red[0] + red[1] + red[2] + red[3];
    const float scale = rsqrtf(tot * (1.0f / C_DIM) + 1e-6f);
#pragma unroll
    for (int i = 0; i < 4; i++) {
        const int c = tid * 4 + i;
        out[(size_t)row * C_DIM + c] = (bf16)(v[i] * scale * w[c]);
    }
}

// ---------------------------------------------------------------------------
// GEMM  out[M,N] = A[M,K](lda) @ B[N,K](ldb)^T  (+ fused epilogue)
// RESID: 0 none | 2 add f32 resid | 3 out = silu(resid_bf16) * acc
// OUTF32: 1 -> write f32, else bf16.  In-place resid==out (f32) is safe:
// epilogue is element-wise read-then-write of the same index.
// MFMA layouts (HW-verified, learn_hip m89/m91):
//   A frag: lane holds A[m=lane&15][k=quad*8+j]  (16B contig)
//   B frag: lane holds B[n=lane&15][k=quad*8+j]  (16B contig)
//   C/D:    col=lane&15, row=quad*4+reg
// ---------------------------------------------------------------------------
template <int SUB, int RESID, int OUTF32>
__global__ __launch_bounds__(256) void gemm_bt(const bf16* __restrict__ A, int lda,
                                               const bf16* __restrict__ B, int ldb,
                                               const void* __restrict__ resid,
                                               void* __restrict__ out,
                                               int N, int K) {
    const int lane = threadIdx.x & 63;
    const int wv = threadIdx.x >> 6;
    const int wm = wv >> 1, wn = wv & 1;
    const int r = lane & 15;
    const int quad = lane >> 4;
    const int mbase = blockIdx.y * (SUB * 32) + wm * (SUB * 16);
    const int nbase = blockIdx.x * (SUB * 32) + wn * (SUB * 16);

    f32x4 acc[SUB][SUB] = {};

    const bf16* Ab = A + (size_t)(mbase + r) * lda + quad * 8;
    const bf16* Bb = B + (size_t)(nbase + r) * ldb + quad * 8;

    for (int k0 = 0; k0 < K; k0 += 32) {
        bf16x8 a[SUB], b[SUB];
#pragma unroll
        for (int i = 0; i < SUB; i++)
            a[i] = *reinterpret_cast<const bf16x8*>(Ab + (size_t)(i * 16) * lda + k0);
#pragma unroll
        for (int j = 0; j < SUB; j++)
            b[j] = *reinterpret_cast<const bf16x8*>(Bb + (size_t)(j * 16) * ldb + k0);
#pragma unroll
        for (int i = 0; i < SUB; i++)
#pragma unroll
            for (int j = 0; j < SUB; j++)
                acc[i][j] = __builtin_amdgcn_mfma_f32_16x16x32_bf16(a[i], b[j], acc[i][j], 0, 0, 0);
    }

#pragma unroll
    for (int i = 0; i < SUB; i++) {
#pragma unroll
        for (int j = 0; j < SUB; j++) {
            const int col = nbase + j * 16 + r;
#pragma unroll
            for (int reg = 0; reg < 4; reg++) {
                const int row = mbase + i * 16 + quad * 4 + reg;
                const size_t idx = (size_t)row * N + col;
                float v = acc[i][j][reg];
                if (RESID == 2) v += ((const float*)resid)[idx];
                if (RESID == 3) {
                    const float a1 = (float)((const bf16*)resid)[idx];
                    v = (a1 / (1.0f + __expf(-a1))) * v;
                }
                if (OUTF32)
                    ((float*)out)[idx] = v;
                else
                    ((bf16*)out)[idx] = (bf16)v;
            }
        }
    }
}

// ---------------------------------------------------------------------------
// Build KT[h][d][t] from qkv's K section (qkv[t][1024 + h*64 + d])
// ---------------------------------------------------------------------------
__global__ __launch_bounds__(256) void build_kt(const bf16* __restrict__ qkv,
                                                bf16* __restrict__ KT) {
    const int h = blockIdx.y;
    const int tb = blockIdx.x;
    __shared__ bf16 tile[64][65];
    const int tx = threadIdx.x & 63;
    const int ty = threadIdx.x >> 6;
    for (int rr = ty; rr < 64; rr += 4)
        tile[rr][tx] = qkv[(size_t)(tb * 64 + rr) * LD_QKV + C_DIM + h * 64 + tx];
    __syncthreads();
    for (int rr = ty; rr < 64; rr += 4)
        KT[((size_t)h * 64 + rr) * T_SEQ + tb * 64 + tx] = tile[tx][rr];
}

// ---------------------------------------------------------------------------
// Causal attention, online softmax. One wave per (t, head).
// ---------------------------------------------------------------------------
__global__ __launch_bounds__(256) void attn_kernel(const bf16* __restrict__ qkv,
                                                   const bf16* __restrict__ KT,
                                                   bf16* __restrict__ y) {
    const int wv = threadIdx.x >> 6;
    const int lane = threadIdx.x & 63;
    const int wg = blockIdx.x * 4 + wv;
    const int h = wg & 15;
    const int t = wg >> 4;

    __shared__ float qs[4][64];
    __shared__ float ps[4][64];

    qs[wv][lane] = (float)qkv[(size_t)t * LD_QKV + h * 64 + lane] * 0.125f;  // 1/sqrt(64)
    __syncthreads();

    float m_i = -1e30f, l_i = 0.f, acc = 0.f;
    const int nkb = (t >> 6) + 1;
    const bf16* Vbase = qkv + 2 * C_DIM + h * 64 + lane;
    const bf16* Kbase = KT + (size_t)h * 64 * T_SEQ;

    for (int kb = 0; kb < nkb; kb++) {
        const int key = kb * 64 + lane;
        float s = 0.f;
        const bf16* kp = Kbase + kb * 64 + lane;
#pragma unroll 8
        for (int d = 0; d < 64; d++) s += qs[wv][d] * (float)kp[(size_t)d * T_SEQ];
        if (key > t) s = -1e30f;

        float sm = s;
#pragma unroll
        for (int off = 32; off; off >>= 1) sm = fmaxf(sm, __shfl_xor(sm, off));
        const float m_new = fmaxf(m_i, sm);
        float p = (key > t) ? 0.f : __expf(s - m_new);
        float psum = p;
#pragma unroll
        for (int off = 32; off; off >>= 1) psum += __shfl_xor(psum, off);
        const float alpha = __expf(m_i - m_new);
        l_i = l_i * alpha + psum;
        acc *= alpha;
        ps[wv][lane] = p;

        const bf16* vp = Vbase + (size_t)(kb * 64) * LD_QKV;
#pragma unroll 8
        for (int l = 0; l < 64; l++) acc += ps[wv][l] * (float)vp[(size_t)l * LD_QKV];
        m_i = m_new;
    }
    y[(size_t)t * C_DIM + h * 64 + lane] = (bf16)(acc / l_i);
}

// ---------------------------------------------------------------------------
// launch.  Inputs f32, output f32 (reference dtypes).  ws peak = 56 MiB:
//   [0, 6)   : cwA (c_attn bf16)          [6, 8)  : cwP (c_proj bf16)
//   [8, 16)  : rms (rms1, later rms2)
//   [16, 40) : qkv bf16                   [40,48) : KT bf16
//   [48, 56) : y bf16
//   FFN phase ([16,48) dead): w1h [16,20) w3h [20,24) w2h [24,28) h1h [28,44)
// xmid lives in d_out (f32, 16 MiB); final GEMMs accumulate into it in place.
// ---------------------------------------------------------------------------
extern "C" void kernel_launch(void* const* d_in, const int* in_sizes, int n_in,
                              void* d_out, int out_size, void* d_ws, size_t ws_size,
                              hipStream_t stream) {
    const float* x        = (const float*)d_in[0];
    const float* attn_w   = (const float*)d_in[1];
    const float* ffn_w    = (const float*)d_in[2];
    const float* c_attn_w = (const float*)d_in[3];
    const float* c_proj_w = (const float*)d_in[4];
    const float* w1       = (const float*)d_in[5];
    const float* w2       = (const float*)d_in[6];
    const float* w3       = (const float*)d_in[7];
    float* xmid = (float*)d_out;  // f32 residual accumulator == final output

    char* ws = (char*)d_ws;
    bf16* cwA = (bf16*)(ws);
    bf16* cwP = (bf16*)(ws + MB(6));
    bf16* rms = (bf16*)(ws + MB(8));
    bf16* qkv = (bf16*)(ws + MB(16));
    bf16* KT  = (bf16*)(ws + MB(40));
    bf16* y   = (bf16*)(ws + MB(48));
    bf16* w1h = (bf16*)(ws + MB(16));
    bf16* w3h = (bf16*)(ws + MB(20));
    bf16* w2h = (bf16*)(ws + MB(24));
    bf16* h1h = (bf16*)(ws + MB(28));

    // 1. attention weights -> bf16
    cvt_w<<<512, 256, 0, stream>>>(c_attn_w, 0, (ushort4*)cwA, 3072 * 1024 / 4);
    cvt_w<<<512, 256, 0, stream>>>(c_proj_w, 0, (ushort4*)cwP, 1024 * 1024 / 4);
    // 2. rms1 = rmsnorm(x, attn_norm_w)
    rmsnorm_k<<<T_SEQ, 256, 0, stream>>>(x, attn_w, rms);
    // 3. qkv = rms1 @ c_attn^T   [4096, 3072]
    gemm_bt<4, 0, 0><<<dim3(24, 32), 256, 0, stream>>>(rms, C_DIM, cwA, C_DIM, nullptr, qkv, 3072, 1024);
    // 4. KT + attention
    build_kt<<<dim3(64, 16), 256, 0, stream>>>(qkv, KT);
    attn_kernel<<<16384, 256, 0, stream>>>(qkv, KT, y);
    // 5. xmid = x + y @ c_proj^T   (f32, into d_out)
    gemm_bt<2, 2, 1><<<dim3(16, 64), 256, 0, stream>>>(y, C_DIM, cwP, C_DIM, x, xmid, 1024, 1024);
    // 6. rms2 = rmsnorm(xmid, ffn_norm_w)
    rmsnorm_k<<<T_SEQ, 256, 0, stream>>>(xmid, ffn_w, rms);
    // 7. FFN in two Hf=2048 halves; w2-partials accumulate into xmid in place.
    for (int hh = 0; hh < 2; hh++) {
        cvt_w<<<512, 256, 0, stream>>>(w1, (size_t)hh * 2048 * 1024, (ushort4*)w1h, 2048 * 1024 / 4);
        gemm_bt<4, 0, 0><<<dim3(16, 32), 256, 0, stream>>>(rms, C_DIM, w1h, C_DIM, nullptr, h1h, 2048, 1024);
        cvt_w<<<512, 256, 0, stream>>>(w3, (size_t)hh * 2048 * 1024, (ushort4*)w3h, 2048 * 1024 / 4);
        gemm_bt<4, 3, 0><<<dim3(16, 32), 256, 0, stream>>>(rms, C_DIM, w3h, C_DIM, h1h, h1h, 2048, 1024);
        cvt_w2h<<<2048, 256, 0, stream>>>(w2, hh * 2048, (ushort4*)w2h);
        // w2h is COMPACTED [1024][2048] -> ldb = 2048 (round-5 bug was ldb=4096)
        gemm_bt<2, 2, 1><<<dim3(16, 64), 256, 0, stream>>>(h1h, 2048, w2h, 2048, xmid, xmid, 1024, 2048);
    }
}

// Round 7
// 1022.376 us; speedup vs baseline: 2.8442x; 2.8442x over previous
//
#include <hip/hip_runtime.h>
#include <hip/hip_bf16.h>

typedef __hip_bfloat16 bf16;
typedef __bf16 bf16r;
typedef bf16r bf16x8 __attribute__((ext_vector_type(8)));
typedef float f32x4 __attribute__((ext_vector_type(4)));

#define T_SEQ 4096
#define C_DIM 1024
#define LD_QKV 3072
#define MB(x) ((size_t)(x) << 20)

static __device__ __forceinline__ unsigned short f2bf(float f) {
    bf16 h = (bf16)f;
    return *reinterpret_cast<unsigned short*>(&h);
}

// ---------------------------------------------------------------------------
// f32 -> bf16 weight convert, contiguous slice (element offset eoff, n4 vec4s)
// ---------------------------------------------------------------------------
__global__ __launch_bounds__(256) void cvt_w(const float* __restrict__ src, size_t eoff,
                                             ushort4* __restrict__ dst, int n4) {
    int i = blockIdx.x * 256 + threadIdx.x;
    const int stride = gridDim.x * 256;
    const float4* s = (const float4*)(src + eoff);
    for (; i < n4; i += stride) {
        float4 v = s[i];
        ushort4 o;
        o.x = f2bf(v.x); o.y = f2bf(v.y); o.z = f2bf(v.z); o.w = f2bf(v.w);
        dst[i] = o;
    }
}

// ---------------------------------------------------------------------------
// w2 column-slice convert: src f32 [1024][4096], cols [coff, coff+2048)
// -> dst bf16 [1024][2048] (compacted, ld = 2048).
// ---------------------------------------------------------------------------
__global__ __launch_bounds__(256) void cvt_w2h(const float* __restrict__ src, int coff,
                                               ushort4* __restrict__ dst) {
    const int i = blockIdx.x * 256 + threadIdx.x;  // [0, 1024*2048/4)
    const int row = i >> 9;
    const int c4 = i & 511;
    float4 v = *(const float4*)(src + (size_t)row * 4096 + coff + c4 * 4);
    ushort4 o;
    o.x = f2bf(v.x); o.y = f2bf(v.y); o.z = f2bf(v.z); o.w = f2bf(v.w);
    dst[i] = o;
}

// ---------------------------------------------------------------------------
// RMSNorm: f32 in, f32 weight, bf16 out. One block per row of 1024.
// ---------------------------------------------------------------------------
__global__ __launch_bounds__(256) void rmsnorm_k(const float* __restrict__ x,
                                                 const float* __restrict__ w,
                                                 bf16* __restrict__ out) {
    const int row = blockIdx.x;
    const int tid = threadIdx.x;
    const float* xr = x + (size_t)row * C_DIM;
    float v[4];
    float ss = 0.f;
#pragma unroll
    for (int i = 0; i < 4; i++) { v[i] = xr[tid * 4 + i]; ss += v[i] * v[i]; }
#pragma unroll
    for (int off = 32; off; off >>= 1) ss += __shfl_xor(ss, off);
    __shared__ float red[4];
    if ((tid & 63) == 0) red[tid >> 6] = ss;
    __syncthreads();
    const float tot = red[0] + red[1] + red[2] + red[3];
    const float scale = rsqrtf(tot * (1.0f / C_DIM) + 1e-6f);
#pragma unroll
    for (int i = 0; i < 4; i++) {
        const int c = tid * 4 + i;
        out[(size_t)row * C_DIM + c] = (bf16)(v[i] * scale * w[c]);
    }
}

// ---------------------------------------------------------------------------
// GEMM  out[M,N] = A[M,K](lda) @ B[N,K](ldb)^T  (+ fused epilogue)
// RESID: 0 none | 2 add f32 resid | 3 out = silu(resid_bf16) * acc
// OUTF32: 1 -> write f32, else bf16.
// MFMA layouts (HW-verified, learn_hip m89/m91):
//   A frag: lane holds A[m=lane&15][k=quad*8+j]  (16B contig)
//   B frag: lane holds B[n=lane&15][k=quad*8+j]  (16B contig)
//   C/D:    col=lane&15, row=quad*4+reg
// ---------------------------------------------------------------------------
template <int SUB, int RESID, int OUTF32>
__global__ __launch_bounds__(256) void gemm_bt(const bf16* __restrict__ A, int lda,
                                               const bf16* __restrict__ B, int ldb,
                                               const void* __restrict__ resid,
                                               void* __restrict__ out,
                                               int N, int K) {
    const int lane = threadIdx.x & 63;
    const int wv = threadIdx.x >> 6;
    const int wm = wv >> 1, wn = wv & 1;
    const int r = lane & 15;
    const int quad = lane >> 4;
    const int mbase = blockIdx.y * (SUB * 32) + wm * (SUB * 16);
    const int nbase = blockIdx.x * (SUB * 32) + wn * (SUB * 16);

    f32x4 acc[SUB][SUB] = {};

    const bf16* Ab = A + (size_t)(mbase + r) * lda + quad * 8;
    const bf16* Bb = B + (size_t)(nbase + r) * ldb + quad * 8;

    for (int k0 = 0; k0 < K; k0 += 32) {
        bf16x8 a[SUB], b[SUB];
#pragma unroll
        for (int i = 0; i < SUB; i++)
            a[i] = *reinterpret_cast<const bf16x8*>(Ab + (size_t)(i * 16) * lda + k0);
#pragma unroll
        for (int j = 0; j < SUB; j++)
            b[j] = *reinterpret_cast<const bf16x8*>(Bb + (size_t)(j * 16) * ldb + k0);
#pragma unroll
        for (int i = 0; i < SUB; i++)
#pragma unroll
            for (int j = 0; j < SUB; j++)
                acc[i][j] = __builtin_amdgcn_mfma_f32_16x16x32_bf16(a[i], b[j], acc[i][j], 0, 0, 0);
    }

#pragma unroll
    for (int i = 0; i < SUB; i++) {
#pragma unroll
        for (int j = 0; j < SUB; j++) {
            const int col = nbase + j * 16 + r;
#pragma unroll
            for (int reg = 0; reg < 4; reg++) {
                const int row = mbase + i * 16 + quad * 4 + reg;
                const size_t idx = (size_t)row * N + col;
                float v = acc[i][j][reg];
                if (RESID == 2) v += ((const float*)resid)[idx];
                if (RESID == 3) {
                    const float a1 = (float)((const bf16*)resid)[idx];
                    v = (a1 / (1.0f + __expf(-a1))) * v;
                }
                if (OUTF32)
                    ((float*)out)[idx] = v;
                else
                    ((bf16*)out)[idx] = (bf16)v;
            }
        }
    }
}

// ---------------------------------------------------------------------------
// Transpose a qkv section to [h][d][t]: dst[(h*64+d)*T + t] = qkv[t][soff+h*64+d]
// ---------------------------------------------------------------------------
__global__ __launch_bounds__(256) void build_tr(const bf16* __restrict__ qkv,
                                                bf16* __restrict__ dst, int soff) {
    const int h = blockIdx.y;
    const int tb = blockIdx.x;
    __shared__ bf16 tile[64][65];
    const int tx = threadIdx.x & 63;
    const int ty = threadIdx.x >> 6;
    for (int rr = ty; rr < 64; rr += 4)
        tile[rr][tx] = qkv[(size_t)(tb * 64 + rr) * LD_QKV + soff + h * 64 + tx];
    __syncthreads();
    for (int rr = ty; rr < 64; rr += 4)
        dst[((size_t)h * 64 + rr) * T_SEQ + tb * 64 + tx] = tile[tx][rr];
}

// ---------------------------------------------------------------------------
// MFMA flash attention. One block per (head, 64-row Q-tile); 4 waves x 16 rows.
// Per 64-key block: stage K [key][d] (B-frag orientation for QK^T) and
// VT [d][key] (B-frag orientation for PV) into LDS; QK^T (8 MFMA) -> online
// softmax in registers (C/D row = quad*4+reg; row stats via shfl over the 16
// col-lanes) -> P through wave-private LDS (C-layout -> A-layout, m120) ->
// PV (8 MFMA into O). Causal mask only in the diagonal block.
// ---------------------------------------------------------------------------
__global__ __launch_bounds__(256) void attn_mfma(const bf16* __restrict__ qkv,
                                                 const bf16* __restrict__ VT,
                                                 bf16* __restrict__ y) {
    __shared__ __align__(16) bf16r Ks[64][72];
    __shared__ __align__(16) bf16r VTs[64][72];
    __shared__ __align__(16) bf16r Ps[4][16][72];

    const int w    = threadIdx.x >> 6;
    const int lane = threadIdx.x & 63;
    const int c    = lane & 15;
    const int qd   = lane >> 4;
    const int h    = blockIdx.y;
    // load-balance swizzle: pair (0,63),(1,62),... so block runtimes even out
    const int xx = blockIdx.x;
    const int qb = (xx & 1) ? (63 - (xx >> 1)) : (xx >> 1);
    const int qbase = qb * 64 + w * 16;

    // Q fragments (A-layout): lane holds Q[qbase + c][ks*32 + qd*8 + j]
    bf16x8 qf[2];
    {
        const bf16* qp = qkv + (size_t)(qbase + c) * LD_QKV + h * 64;
        qf[0] = *(const bf16x8*)(qp + qd * 8);
        qf[1] = *(const bf16x8*)(qp + 32 + qd * 8);
    }

    f32x4 O[4] = {};
    float m_i[4], l_i[4];
#pragma unroll
    for (int r = 0; r < 4; r++) { m_i[r] = -1e30f; l_i[r] = 0.f; }

    for (int kb = 0; kb <= qb; kb++) {
        // ---- cooperative staging: K tile + VT tile (8 KB each) ----
        for (int i = threadIdx.x; i < 512; i += 256) {
            const int row = i >> 3, ch = i & 7;
            *(bf16x8*)&Ks[row][ch * 8] =
                *(const bf16x8*)(qkv + (size_t)(kb * 64 + row) * LD_QKV + C_DIM + h * 64 + ch * 8);
            *(bf16x8*)&VTs[row][ch * 8] =
                *(const bf16x8*)(VT + ((size_t)h * 64 + row) * T_SEQ + kb * 64 + ch * 8);
        }
        __syncthreads();

        // ---- S = Q K^T (16 rows x 64 keys per wave) ----
        f32x4 S[4] = {};
#pragma unroll
        for (int ks = 0; ks < 2; ks++)
#pragma unroll
            for (int nt = 0; nt < 4; nt++) {
                bf16x8 kf = *(const bf16x8*)&Ks[nt * 16 + c][ks * 32 + qd * 8];
                S[nt] = __builtin_amdgcn_mfma_f32_16x16x32_bf16(qf[ks], kf, S[nt], 0, 0, 0);
            }

        // ---- scale (+ causal mask on the diagonal block) ----
        if (kb == qb) {
#pragma unroll
            for (int nt = 0; nt < 4; nt++)
#pragma unroll
                for (int r = 0; r < 4; r++) {
                    float s = S[nt][r] * 0.125f;
                    if (kb * 64 + nt * 16 + c > qbase + qd * 4 + r) s = -1e30f;
                    S[nt][r] = s;
                }
        } else {
#pragma unroll
            for (int nt = 0; nt < 4; nt++)
#pragma unroll
                for (int r = 0; r < 4; r++) S[nt][r] *= 0.125f;
        }

        // ---- online softmax row stats (rows live in reg index; cols across
        //      the 16 lanes with the same quad) ----
        float alpha[4];
#pragma unroll
        for (int r = 0; r < 4; r++) {
            float mb = fmaxf(fmaxf(S[0][r], S[1][r]), fmaxf(S[2][r], S[3][r]));
#pragma unroll
            for (int msk = 1; msk < 16; msk <<= 1) mb = fmaxf(mb, __shfl_xor(mb, msk));
            const float mnew = fmaxf(m_i[r], mb);
            alpha[r] = __expf(m_i[r] - mnew);
            m_i[r] = mnew;
        }
#pragma unroll
        for (int nt = 0; nt < 4; nt++)
#pragma unroll
            for (int r = 0; r < 4; r++) S[nt][r] = __expf(S[nt][r] - m_i[r]);
#pragma unroll
        for (int r = 0; r < 4; r++) {
            float rs = S[0][r] + S[1][r] + S[2][r] + S[3][r];
#pragma unroll
            for (int msk = 1; msk < 16; msk <<= 1) rs += __shfl_xor(rs, msk);
            l_i[r] = l_i[r] * alpha[r] + rs;
        }
#pragma unroll
        for (int nt = 0; nt < 4; nt++)
#pragma unroll
            for (int r = 0; r < 4; r++) O[nt][r] *= alpha[r];

        // ---- P: C/D layout -> A layout via wave-private LDS ----
#pragma unroll
        for (int nt = 0; nt < 4; nt++)
#pragma unroll
            for (int r = 0; r < 4; r++)
                Ps[w][qd * 4 + r][nt * 16 + c] = (bf16r)S[nt][r];

        // ---- O += P V  (A = P[q][key], B = VT[d][key]) ----
#pragma unroll
        for (int ks = 0; ks < 2; ks++) {
            bf16x8 pf = *(const bf16x8*)&Ps[w][c][ks * 32 + qd * 8];
#pragma unroll
            for (int nt = 0; nt < 4; nt++) {
                bf16x8 vf = *(const bf16x8*)&VTs[nt * 16 + c][ks * 32 + qd * 8];
                O[nt] = __builtin_amdgcn_mfma_f32_16x16x32_bf16(pf, vf, O[nt], 0, 0, 0);
            }
        }
        __syncthreads();
    }

    // ---- epilogue: y[q][h*64 + d] = O / l ----
#pragma unroll
    for (int nt = 0; nt < 4; nt++)
#pragma unroll
        for (int r = 0; r < 4; r++)
            y[(size_t)(qbase + qd * 4 + r) * C_DIM + h * 64 + nt * 16 + c] =
                (bf16)(O[nt][r] / l_i[r]);
}

// ---------------------------------------------------------------------------
// launch.  Inputs f32, output f32.  ws peak = 56 MiB:
//   [0, 6)   : cwA (c_attn bf16)          [6, 8)  : cwP (c_proj bf16)
//   [8, 16)  : rms (rms1, later rms2)
//   [16, 40) : qkv bf16                   [40,48) : VT bf16 (V transposed)
//   [48, 56) : y bf16
//   FFN phase ([16,48) dead): w1h [16,20) w3h [20,24) w2h [24,28) h1h [28,44)
// xmid lives in d_out (f32); final GEMMs accumulate into it in place.
// ---------------------------------------------------------------------------
extern "C" void kernel_launch(void* const* d_in, const int* in_sizes, int n_in,
                              void* d_out, int out_size, void* d_ws, size_t ws_size,
                              hipStream_t stream) {
    const float* x        = (const float*)d_in[0];
    const float* attn_w   = (const float*)d_in[1];
    const float* ffn_w    = (const float*)d_in[2];
    const float* c_attn_w = (const float*)d_in[3];
    const float* c_proj_w = (const float*)d_in[4];
    const float* w1       = (const float*)d_in[5];
    const float* w2       = (const float*)d_in[6];
    const float* w3       = (const float*)d_in[7];
    float* xmid = (float*)d_out;

    char* ws = (char*)d_ws;
    bf16* cwA = (bf16*)(ws);
    bf16* cwP = (bf16*)(ws + MB(6));
    bf16* rms = (bf16*)(ws + MB(8));
    bf16* qkv = (bf16*)(ws + MB(16));
    bf16* VT  = (bf16*)(ws + MB(40));
    bf16* y   = (bf16*)(ws + MB(48));
    bf16* w1h = (bf16*)(ws + MB(16));
    bf16* w3h = (bf16*)(ws + MB(20));
    bf16* w2h = (bf16*)(ws + MB(24));
    bf16* h1h = (bf16*)(ws + MB(28));

    // 1. attention weights -> bf16
    cvt_w<<<512, 256, 0, stream>>>(c_attn_w, 0, (ushort4*)cwA, 3072 * 1024 / 4);
    cvt_w<<<512, 256, 0, stream>>>(c_proj_w, 0, (ushort4*)cwP, 1024 * 1024 / 4);
    // 2. rms1 = rmsnorm(x, attn_norm_w)
    rmsnorm_k<<<T_SEQ, 256, 0, stream>>>(x, attn_w, rms);
    // 3. qkv = rms1 @ c_attn^T   [4096, 3072]
    gemm_bt<4, 0, 0><<<dim3(24, 32), 256, 0, stream>>>(rms, C_DIM, cwA, C_DIM, nullptr, qkv, 3072, 1024);
    // 4. VT (V transposed per head) + MFMA flash attention
    build_tr<<<dim3(64, 16), 256, 0, stream>>>(qkv, VT, 2 * C_DIM);
    attn_mfma<<<dim3(64, 16), 256, 0, stream>>>(qkv, VT, y);
    // 5. xmid = x + y @ c_proj^T   (f32, into d_out)
    gemm_bt<2, 2, 1><<<dim3(16, 64), 256, 0, stream>>>(y, C_DIM, cwP, C_DIM, x, xmid, 1024, 1024);
    // 6. rms2 = rmsnorm(xmid, ffn_norm_w)
    rmsnorm_k<<<T_SEQ, 256, 0, stream>>>(xmid, ffn_w, rms);
    // 7. FFN in two Hf=2048 halves; w2-partials accumulate into xmid in place.
    for (int hh = 0; hh < 2; hh++) {
        cvt_w<<<512, 256, 0, stream>>>(w1, (size_t)hh * 2048 * 1024, (ushort4*)w1h, 2048 * 1024 / 4);
        gemm_bt<4, 0, 0><<<dim3(16, 32), 256, 0, stream>>>(rms, C_DIM, w1h, C_DIM, nullptr, h1h, 2048, 1024);
        cvt_w<<<512, 256, 0, stream>>>(w3, (size_t)hh * 2048 * 1024, (ushort4*)w3h, 2048 * 1024 / 4);
        gemm_bt<4, 3, 0><<<dim3(16, 32), 256, 0, stream>>>(rms, C_DIM, w3h, C_DIM, h1h, h1h, 2048, 1024);
        cvt_w2h<<<2048, 256, 0, stream>>>(w2, hh * 2048, (ushort4*)w2h);
        gemm_bt<2, 2, 1><<<dim3(16, 64), 256, 0, stream>>>(h1h, 2048, w2h, 2048, xmid, xmid, 1024, 2048);
    }
}

// Round 8
// 671.106 us; speedup vs baseline: 4.3329x; 1.5234x over previous
//
#include <hip/hip_runtime.h>
#include <hip/hip_bf16.h>

typedef __hip_bfloat16 bf16;
typedef __bf16 bf16r;
typedef bf16r bf16x8 __attribute__((ext_vector_type(8)));
typedef float f32x4 __attribute__((ext_vector_type(4)));

#define T_SEQ 4096
#define C_DIM 1024
#define LD_QKV 3072
#define MB(x) ((size_t)(x) << 20)

static __device__ __forceinline__ unsigned short f2bf(float f) {
    bf16 h = (bf16)f;
    return *reinterpret_cast<unsigned short*>(&h);
}

// ---------------------------------------------------------------------------
// f32 -> bf16 weight convert, contiguous slice
// ---------------------------------------------------------------------------
__global__ __launch_bounds__(256) void cvt_w(const float* __restrict__ src, size_t eoff,
                                             ushort4* __restrict__ dst, int n4) {
    int i = blockIdx.x * 256 + threadIdx.x;
    const int stride = gridDim.x * 256;
    const float4* s = (const float4*)(src + eoff);
    for (; i < n4; i += stride) {
        float4 v = s[i];
        ushort4 o;
        o.x = f2bf(v.x); o.y = f2bf(v.y); o.z = f2bf(v.z); o.w = f2bf(v.w);
        dst[i] = o;
    }
}

// ---------------------------------------------------------------------------
// w2 column-slice convert: src f32 [1024][4096], cols [coff, coff+2048)
// -> dst bf16 [1024][2048] (compacted, ld = 2048).
// ---------------------------------------------------------------------------
__global__ __launch_bounds__(256) void cvt_w2h(const float* __restrict__ src, int coff,
                                               ushort4* __restrict__ dst) {
    const int i = blockIdx.x * 256 + threadIdx.x;
    const int row = i >> 9;
    const int c4 = i & 511;
    float4 v = *(const float4*)(src + (size_t)row * 4096 + coff + c4 * 4);
    ushort4 o;
    o.x = f2bf(v.x); o.y = f2bf(v.y); o.z = f2bf(v.z); o.w = f2bf(v.w);
    dst[i] = o;
}

// ---------------------------------------------------------------------------
// RMSNorm: f32 in, f32 weight, bf16 out. One block per row of 1024.
// ---------------------------------------------------------------------------
__global__ __launch_bounds__(256) void rmsnorm_k(const float* __restrict__ x,
                                                 const float* __restrict__ w,
                                                 bf16* __restrict__ out) {
    const int row = blockIdx.x;
    const int tid = threadIdx.x;
    const float* xr = x + (size_t)row * C_DIM;
    float v[4];
    float ss = 0.f;
#pragma unroll
    for (int i = 0; i < 4; i++) { v[i] = xr[tid * 4 + i]; ss += v[i] * v[i]; }
#pragma unroll
    for (int off = 32; off; off >>= 1) ss += __shfl_xor(ss, off);
    __shared__ float red[4];
    if ((tid & 63) == 0) red[tid >> 6] = ss;
    __syncthreads();
    const float tot = red[0] + red[1] + red[2] + red[3];
    const float scale = rsqrtf(tot * (1.0f / C_DIM) + 1e-6f);
#pragma unroll
    for (int i = 0; i < 4; i++) {
        const int c = tid * 4 + i;
        out[(size_t)row * C_DIM + c] = (bf16)(v[i] * scale * w[c]);
    }
}

// ---------------------------------------------------------------------------
// m97-structure GEMM: out[M,N] = A[M,K](lda) @ B[N,K](ldb)^T (+ epilogue)
// 256 thr = 4 waves; block tile 128x128; wave tile 64x64 (4x4 MFMAs); BK=32.
// Staging via global_load_lds width=16: LDS is contiguous [128][32] per tile,
// wave-uniform base + lane*16 (lane l -> row l/4, chunk l%4). No padding
// (m104/m108: global_load_lds cannot scatter past lane*size).
// RESID: 0 none | 2 add f32 resid | 3 out = silu(resid_bf16) * acc
// OUTF32: 1 -> write f32, else bf16.
// ---------------------------------------------------------------------------
template <int RESID, int OUTF32>
__global__ __launch_bounds__(256) void gemm128(const bf16* __restrict__ A, int lda,
                                               const bf16* __restrict__ B, int ldb,
                                               const void* __restrict__ resid,
                                               void* __restrict__ out,
                                               int N, int K) {
    __shared__ __align__(16) bf16r As[128 * 32];
    __shared__ __align__(16) bf16r Bs[128 * 32];
    const int tid = threadIdx.x;
    const int w = tid >> 6, lane = tid & 63;
    const int c = lane & 15, qd = lane >> 4;
    const int wm = w >> 1, wn = w & 1;
    const int mbase = blockIdx.y * 128;
    const int nbase = blockIdx.x * 128;

    const int srow = lane >> 2, schk = lane & 3;  // staging: 16 rows x 4 chunks per instr
    const bf16* gA = A + (size_t)(mbase + w * 32 + srow) * lda + schk * 8;
    const bf16* gB = B + (size_t)(nbase + w * 32 + srow) * ldb + schk * 8;

    f32x4 acc[4][4] = {};

    for (int k0 = 0; k0 < K; k0 += 32) {
        __syncthreads();  // previous iter's LDS reads complete
#pragma unroll
        for (int s = 0; s < 2; s++) {
            __builtin_amdgcn_global_load_lds(
                (const __attribute__((address_space(1))) void*)(gA + (size_t)(s * 16) * lda + k0),
                (__attribute__((address_space(3))) void*)&As[(w * 32 + s * 16) * 32], 16, 0, 0);
            __builtin_amdgcn_global_load_lds(
                (const __attribute__((address_space(1))) void*)(gB + (size_t)(s * 16) * ldb + k0),
                (__attribute__((address_space(3))) void*)&Bs[(w * 32 + s * 16) * 32], 16, 0, 0);
        }
        __syncthreads();  // drains vmcnt before barrier (compiler-inserted)

        bf16x8 a[4], b[4];
#pragma unroll
        for (int i = 0; i < 4; i++)
            a[i] = *(const bf16x8*)&As[(wm * 64 + i * 16 + c) * 32 + qd * 8];
#pragma unroll
        for (int j = 0; j < 4; j++)
            b[j] = *(const bf16x8*)&Bs[(wn * 64 + j * 16 + c) * 32 + qd * 8];
#pragma unroll
        for (int i = 0; i < 4; i++)
#pragma unroll
            for (int j = 0; j < 4; j++)
                acc[i][j] = __builtin_amdgcn_mfma_f32_16x16x32_bf16(a[i], b[j], acc[i][j], 0, 0, 0);
    }

#pragma unroll
    for (int i = 0; i < 4; i++) {
#pragma unroll
        for (int j = 0; j < 4; j++) {
            const int col = nbase + wn * 64 + j * 16 + c;
#pragma unroll
            for (int reg = 0; reg < 4; reg++) {
                const int row = mbase + wm * 64 + i * 16 + qd * 4 + reg;
                const size_t idx = (size_t)row * N + col;
                float v = acc[i][j][reg];
                if (RESID == 2) v += ((const float*)resid)[idx];
                if (RESID == 3) {
                    const float a1 = (float)((const bf16*)resid)[idx];
                    v = (a1 / (1.0f + __expf(-a1))) * v;
                }
                if (OUTF32)
                    ((float*)out)[idx] = v;
                else
                    ((bf16*)out)[idx] = (bf16)v;
            }
        }
    }
}

// ---------------------------------------------------------------------------
// Transpose a qkv section to [h][d][t]
// ---------------------------------------------------------------------------
__global__ __launch_bounds__(256) void build_tr(const bf16* __restrict__ qkv,
                                                bf16* __restrict__ dst, int soff) {
    const int h = blockIdx.y;
    const int tb = blockIdx.x;
    __shared__ bf16 tile[64][65];
    const int tx = threadIdx.x & 63;
    const int ty = threadIdx.x >> 6;
    for (int rr = ty; rr < 64; rr += 4)
        tile[rr][tx] = qkv[(size_t)(tb * 64 + rr) * LD_QKV + soff + h * 64 + tx];
    __syncthreads();
    for (int rr = ty; rr < 64; rr += 4)
        dst[((size_t)h * 64 + rr) * T_SEQ + tb * 64 + tx] = tile[tx][rr];
}

// ---------------------------------------------------------------------------
// MFMA flash attention (unchanged from round 7). One block per (head, 64-row
// Q-tile); 4 waves x 16 rows.
// ---------------------------------------------------------------------------
__global__ __launch_bounds__(256) void attn_mfma(const bf16* __restrict__ qkv,
                                                 const bf16* __restrict__ VT,
                                                 bf16* __restrict__ y) {
    __shared__ __align__(16) bf16r Ks[64][72];
    __shared__ __align__(16) bf16r VTs[64][72];
    __shared__ __align__(16) bf16r Ps[4][16][72];

    const int w    = threadIdx.x >> 6;
    const int lane = threadIdx.x & 63;
    const int c    = lane & 15;
    const int qd   = lane >> 4;
    const int h    = blockIdx.y;
    const int xx = blockIdx.x;
    const int qb = (xx & 1) ? (63 - (xx >> 1)) : (xx >> 1);
    const int qbase = qb * 64 + w * 16;

    bf16x8 qf[2];
    {
        const bf16* qp = qkv + (size_t)(qbase + c) * LD_QKV + h * 64;
        qf[0] = *(const bf16x8*)(qp + qd * 8);
        qf[1] = *(const bf16x8*)(qp + 32 + qd * 8);
    }

    f32x4 O[4] = {};
    float m_i[4], l_i[4];
#pragma unroll
    for (int r = 0; r < 4; r++) { m_i[r] = -1e30f; l_i[r] = 0.f; }

    for (int kb = 0; kb <= qb; kb++) {
        for (int i = threadIdx.x; i < 512; i += 256) {
            const int row = i >> 3, ch = i & 7;
            *(bf16x8*)&Ks[row][ch * 8] =
                *(const bf16x8*)(qkv + (size_t)(kb * 64 + row) * LD_QKV + C_DIM + h * 64 + ch * 8);
            *(bf16x8*)&VTs[row][ch * 8] =
                *(const bf16x8*)(VT + ((size_t)h * 64 + row) * T_SEQ + kb * 64 + ch * 8);
        }
        __syncthreads();

        f32x4 S[4] = {};
#pragma unroll
        for (int ks = 0; ks < 2; ks++)
#pragma unroll
            for (int nt = 0; nt < 4; nt++) {
                bf16x8 kf = *(const bf16x8*)&Ks[nt * 16 + c][ks * 32 + qd * 8];
                S[nt] = __builtin_amdgcn_mfma_f32_16x16x32_bf16(qf[ks], kf, S[nt], 0, 0, 0);
            }

        if (kb == qb) {
#pragma unroll
            for (int nt = 0; nt < 4; nt++)
#pragma unroll
                for (int r = 0; r < 4; r++) {
                    float s = S[nt][r] * 0.125f;
                    if (kb * 64 + nt * 16 + c > qbase + qd * 4 + r) s = -1e30f;
                    S[nt][r] = s;
                }
        } else {
#pragma unroll
            for (int nt = 0; nt < 4; nt++)
#pragma unroll
                for (int r = 0; r < 4; r++) S[nt][r] *= 0.125f;
        }

        float alpha[4];
#pragma unroll
        for (int r = 0; r < 4; r++) {
            float mb = fmaxf(fmaxf(S[0][r], S[1][r]), fmaxf(S[2][r], S[3][r]));
#pragma unroll
            for (int msk = 1; msk < 16; msk <<= 1) mb = fmaxf(mb, __shfl_xor(mb, msk));
            const float mnew = fmaxf(m_i[r], mb);
            alpha[r] = __expf(m_i[r] - mnew);
            m_i[r] = mnew;
        }
#pragma unroll
        for (int nt = 0; nt < 4; nt++)
#pragma unroll
            for (int r = 0; r < 4; r++) S[nt][r] = __expf(S[nt][r] - m_i[r]);
#pragma unroll
        for (int r = 0; r < 4; r++) {
            float rs = S[0][r] + S[1][r] + S[2][r] + S[3][r];
#pragma unroll
            for (int msk = 1; msk < 16; msk <<= 1) rs += __shfl_xor(rs, msk);
            l_i[r] = l_i[r] * alpha[r] + rs;
        }
#pragma unroll
        for (int nt = 0; nt < 4; nt++)
#pragma unroll
            for (int r = 0; r < 4; r++) O[nt][r] *= alpha[r];

#pragma unroll
        for (int nt = 0; nt < 4; nt++)
#pragma unroll
            for (int r = 0; r < 4; r++)
                Ps[w][qd * 4 + r][nt * 16 + c] = (bf16r)S[nt][r];

#pragma unroll
        for (int ks = 0; ks < 2; ks++) {
            bf16x8 pf = *(const bf16x8*)&Ps[w][c][ks * 32 + qd * 8];
#pragma unroll
            for (int nt = 0; nt < 4; nt++) {
                bf16x8 vf = *(const bf16x8*)&VTs[nt * 16 + c][ks * 32 + qd * 8];
                O[nt] = __builtin_amdgcn_mfma_f32_16x16x32_bf16(pf, vf, O[nt], 0, 0, 0);
            }
        }
        __syncthreads();
    }

#pragma unroll
    for (int nt = 0; nt < 4; nt++)
#pragma unroll
        for (int r = 0; r < 4; r++)
            y[(size_t)(qbase + qd * 4 + r) * C_DIM + h * 64 + nt * 16 + c] =
                (bf16)(O[nt][r] / l_i[r]);
}

// ---------------------------------------------------------------------------
// launch.  Inputs f32, output f32.  ws peak = 56 MiB (same as round 7).
// ---------------------------------------------------------------------------
extern "C" void kernel_launch(void* const* d_in, const int* in_sizes, int n_in,
                              void* d_out, int out_size, void* d_ws, size_t ws_size,
                              hipStream_t stream) {
    const float* x        = (const float*)d_in[0];
    const float* attn_w   = (const float*)d_in[1];
    const float* ffn_w    = (const float*)d_in[2];
    const float* c_attn_w = (const float*)d_in[3];
    const float* c_proj_w = (const float*)d_in[4];
    const float* w1       = (const float*)d_in[5];
    const float* w2       = (const float*)d_in[6];
    const float* w3       = (const float*)d_in[7];
    float* xmid = (float*)d_out;

    char* ws = (char*)d_ws;
    bf16* cwA = (bf16*)(ws);
    bf16* cwP = (bf16*)(ws + MB(6));
    bf16* rms = (bf16*)(ws + MB(8));
    bf16* qkv = (bf16*)(ws + MB(16));
    bf16* VT  = (bf16*)(ws + MB(40));
    bf16* y   = (bf16*)(ws + MB(48));
    bf16* w1h = (bf16*)(ws + MB(16));
    bf16* w3h = (bf16*)(ws + MB(20));
    bf16* w2h = (bf16*)(ws + MB(24));
    bf16* h1h = (bf16*)(ws + MB(28));

    // 1. attention weights -> bf16
    cvt_w<<<512, 256, 0, stream>>>(c_attn_w, 0, (ushort4*)cwA, 3072 * 1024 / 4);
    cvt_w<<<512, 256, 0, stream>>>(c_proj_w, 0, (ushort4*)cwP, 1024 * 1024 / 4);
    // 2. rms1 = rmsnorm(x, attn_norm_w)
    rmsnorm_k<<<T_SEQ, 256, 0, stream>>>(x, attn_w, rms);
    // 3. qkv = rms1 @ c_attn^T   [4096, 3072]
    gemm128<0, 0><<<dim3(24, 32), 256, 0, stream>>>(rms, C_DIM, cwA, C_DIM, nullptr, qkv, 3072, 1024);
    // 4. VT (V transposed per head) + MFMA flash attention
    build_tr<<<dim3(64, 16), 256, 0, stream>>>(qkv, VT, 2 * C_DIM);
    attn_mfma<<<dim3(64, 16), 256, 0, stream>>>(qkv, VT, y);
    // 5. xmid = x + y @ c_proj^T   (f32, into d_out)
    gemm128<2, 1><<<dim3(8, 32), 256, 0, stream>>>(y, C_DIM, cwP, C_DIM, x, xmid, 1024, 1024);
    // 6. rms2 = rmsnorm(xmid, ffn_norm_w)
    rmsnorm_k<<<T_SEQ, 256, 0, stream>>>(xmid, ffn_w, rms);
    // 7. FFN in two Hf=2048 halves; w2-partials accumulate into xmid in place.
    for (int hh = 0; hh < 2; hh++) {
        cvt_w<<<512, 256, 0, stream>>>(w1, (size_t)hh * 2048 * 1024, (ushort4*)w1h, 2048 * 1024 / 4);
        gemm128<0, 0><<<dim3(16, 32), 256, 0, stream>>>(rms, C_DIM, w1h, C_DIM, nullptr, h1h, 2048, 1024);
        cvt_w<<<512, 256, 0, stream>>>(w3, (size_t)hh * 2048 * 1024, (ushort4*)w3h, 2048 * 1024 / 4);
        gemm128<3, 0><<<dim3(16, 32), 256, 0, stream>>>(rms, C_DIM, w3h, C_DIM, h1h, h1h, 2048, 1024);
        cvt_w2h<<<2048, 256, 0, stream>>>(w2, hh * 2048, (ushort4*)w2h);
        gemm128<2, 1><<<dim3(8, 32), 256, 0, stream>>>(h1h, 2048, w2h, 2048, xmid, xmid, 1024, 2048);
    }
}

// Round 9
// 553.011 us; speedup vs baseline: 5.2582x; 1.2135x over previous
//
#include <hip/hip_runtime.h>
#include <hip/hip_bf16.h>

typedef __hip_bfloat16 bf16;
typedef __bf16 bf16r;
typedef bf16r bf16x8 __attribute__((ext_vector_type(8)));
typedef bf16r bf16x4 __attribute__((ext_vector_type(4)));
typedef float f32x4 __attribute__((ext_vector_type(4)));

#define T_SEQ 4096
#define C_DIM 1024
#define LD_QKV 3072
#define MB(x) ((size_t)(x) << 20)

static __device__ __forceinline__ unsigned short f2bf(float f) {
    bf16 h = (bf16)f;
    return *reinterpret_cast<unsigned short*>(&h);
}

// ---------------------------------------------------------------------------
// f32 -> bf16 weight convert, contiguous slice
// ---------------------------------------------------------------------------
__global__ __launch_bounds__(256) void cvt_w(const float* __restrict__ src, size_t eoff,
                                             ushort4* __restrict__ dst, int n4) {
    int i = blockIdx.x * 256 + threadIdx.x;
    const int stride = gridDim.x * 256;
    const float4* s = (const float4*)(src + eoff);
    for (; i < n4; i += stride) {
        float4 v = s[i];
        ushort4 o;
        o.x = f2bf(v.x); o.y = f2bf(v.y); o.z = f2bf(v.z); o.w = f2bf(v.w);
        dst[i] = o;
    }
}

// ---------------------------------------------------------------------------
// w2 column-slice convert: src f32 [1024][4096], cols [coff, coff+2048)
// -> dst bf16 [1024][2048] (compacted, ld = 2048).
// ---------------------------------------------------------------------------
__global__ __launch_bounds__(256) void cvt_w2h(const float* __restrict__ src, int coff,
                                               ushort4* __restrict__ dst) {
    const int i = blockIdx.x * 256 + threadIdx.x;
    const int row = i >> 9;
    const int c4 = i & 511;
    float4 v = *(const float4*)(src + (size_t)row * 4096 + coff + c4 * 4);
    ushort4 o;
    o.x = f2bf(v.x); o.y = f2bf(v.y); o.z = f2bf(v.z); o.w = f2bf(v.w);
    dst[i] = o;
}

// ---------------------------------------------------------------------------
// RMSNorm: f32 in, f32 weight, bf16 out. One block per row of 1024.
// ---------------------------------------------------------------------------
__global__ __launch_bounds__(256) void rmsnorm_k(const float* __restrict__ x,
                                                 const float* __restrict__ w,
                                                 bf16* __restrict__ out) {
    const int row = blockIdx.x;
    const int tid = threadIdx.x;
    const float* xr = x + (size_t)row * C_DIM;
    float v[4];
    float ss = 0.f;
#pragma unroll
    for (int i = 0; i < 4; i++) { v[i] = xr[tid * 4 + i]; ss += v[i] * v[i]; }
#pragma unroll
    for (int off = 32; off; off >>= 1) ss += __shfl_xor(ss, off);
    __shared__ float red[4];
    if ((tid & 63) == 0) red[tid >> 6] = ss;
    __syncthreads();
    const float tot = red[0] + red[1] + red[2] + red[3];
    const float scale = rsqrtf(tot * (1.0f / C_DIM) + 1e-6f);
#pragma unroll
    for (int i = 0; i < 4; i++) {
        const int c = tid * 4 + i;
        out[(size_t)row * C_DIM + c] = (bf16)(v[i] * scale * w[c]);
    }
}

// ---------------------------------------------------------------------------
// m97-structure GEMM: out[M,N] = A[M,K](lda) @ B[N,K](ldb)^T (+ epilogue)
// (unchanged from round 8)
// ---------------------------------------------------------------------------
template <int RESID, int OUTF32>
__global__ __launch_bounds__(256) void gemm128(const bf16* __restrict__ A, int lda,
                                               const bf16* __restrict__ B, int ldb,
                                               const void* __restrict__ resid,
                                               void* __restrict__ out,
                                               int N, int K) {
    __shared__ __align__(16) bf16r As[128 * 32];
    __shared__ __align__(16) bf16r Bs[128 * 32];
    const int tid = threadIdx.x;
    const int w = tid >> 6, lane = tid & 63;
    const int c = lane & 15, qd = lane >> 4;
    const int wm = w >> 1, wn = w & 1;
    const int mbase = blockIdx.y * 128;
    const int nbase = blockIdx.x * 128;

    const int srow = lane >> 2, schk = lane & 3;
    const bf16* gA = A + (size_t)(mbase + w * 32 + srow) * lda + schk * 8;
    const bf16* gB = B + (size_t)(nbase + w * 32 + srow) * ldb + schk * 8;

    f32x4 acc[4][4] = {};

    for (int k0 = 0; k0 < K; k0 += 32) {
        __syncthreads();
#pragma unroll
        for (int s = 0; s < 2; s++) {
            __builtin_amdgcn_global_load_lds(
                (const __attribute__((address_space(1))) void*)(gA + (size_t)(s * 16) * lda + k0),
                (__attribute__((address_space(3))) void*)&As[(w * 32 + s * 16) * 32], 16, 0, 0);
            __builtin_amdgcn_global_load_lds(
                (const __attribute__((address_space(1))) void*)(gB + (size_t)(s * 16) * ldb + k0),
                (__attribute__((address_space(3))) void*)&Bs[(w * 32 + s * 16) * 32], 16, 0, 0);
        }
        __syncthreads();

        bf16x8 a[4], b[4];
#pragma unroll
        for (int i = 0; i < 4; i++)
            a[i] = *(const bf16x8*)&As[(wm * 64 + i * 16 + c) * 32 + qd * 8];
#pragma unroll
        for (int j = 0; j < 4; j++)
            b[j] = *(const bf16x8*)&Bs[(wn * 64 + j * 16 + c) * 32 + qd * 8];
#pragma unroll
        for (int i = 0; i < 4; i++)
#pragma unroll
            for (int j = 0; j < 4; j++)
                acc[i][j] = __builtin_amdgcn_mfma_f32_16x16x32_bf16(a[i], b[j], acc[i][j], 0, 0, 0);
    }

#pragma unroll
    for (int i = 0; i < 4; i++) {
#pragma unroll
        for (int j = 0; j < 4; j++) {
            const int col = nbase + wn * 64 + j * 16 + c;
#pragma unroll
            for (int reg = 0; reg < 4; reg++) {
                const int row = mbase + wm * 64 + i * 16 + qd * 4 + reg;
                const size_t idx = (size_t)row * N + col;
                float v = acc[i][j][reg];
                if (RESID == 2) v += ((const float*)resid)[idx];
                if (RESID == 3) {
                    const float a1 = (float)((const bf16*)resid)[idx];
                    v = (a1 / (1.0f + __expf(-a1))) * v;
                }
                if (OUTF32)
                    ((float*)out)[idx] = v;
                else
                    ((bf16*)out)[idx] = (bf16)v;
            }
        }
    }
}

// ---------------------------------------------------------------------------
// Transpose a qkv section to [h][d][t]
// ---------------------------------------------------------------------------
__global__ __launch_bounds__(256) void build_tr(const bf16* __restrict__ qkv,
                                                bf16* __restrict__ dst, int soff) {
    const int h = blockIdx.y;
    const int tb = blockIdx.x;
    __shared__ bf16 tile[64][65];
    const int tx = threadIdx.x & 63;
    const int ty = threadIdx.x >> 6;
    for (int rr = ty; rr < 64; rr += 4)
        tile[rr][tx] = qkv[(size_t)(tb * 64 + rr) * LD_QKV + soff + h * 64 + tx];
    __syncthreads();
    for (int rr = ty; rr < 64; rr += 4)
        dst[((size_t)h * 64 + rr) * T_SEQ + tb * 64 + tx] = tile[tx][rr];
}

// ---------------------------------------------------------------------------
// MFMA flash attention v2. One block per (head, 64-row Q-tile); 4 waves x
// 16 Q-rows; KB=128 keys/iteration.
// Computes S^T = K Q^T (A=K-frag, B=Q-frag) so row-softmax stats are per-lane
// scalars (q = lane&15) and P^T writes are 8B vectors; then O^T = VT P^T so
// O/l/alpha all index q by lane&15 and y stores are 8B vectors.
// LDS tiles are unpadded with XOR chunk swizzle (chunk ^ (row&7), 16B gran):
// conflict-free reads/writes, 48 KB total -> 3 blocks/CU.
// Only the last (diagonal) 128-key chunk needs causal masking: for kb<nkb-1
// max staged key = kb*128+127 < qb*64 = min q of the tile (proof in notes).
// ---------------------------------------------------------------------------
__global__ __launch_bounds__(256) void attn_mfma(const bf16* __restrict__ qkv,
                                                 const bf16* __restrict__ VT,
                                                 bf16* __restrict__ y) {
    __shared__ __align__(16) bf16r Ks[128][64];    // keys x d
    __shared__ __align__(16) bf16r VTs[64][128];   // d x keys
    __shared__ __align__(16) bf16r Ps[4][16][128]; // per-wave q x keys

    const int w    = threadIdx.x >> 6;
    const int lane = threadIdx.x & 63;
    const int c    = lane & 15;
    const int qd   = lane >> 4;
    const int id   = blockIdx.x;
    const int h    = id & 15;          // head fastest: same-CU blocks differ in qb
    const int qt   = id >> 4;          // 0..63
    const int qb   = (qt & 1) ? (63 - (qt >> 1)) : (qt >> 1);  // heavy/light pairing
    const int qrow = qb * 64 + w * 16 + c;
    const int sw   = c & 7;            // xor swizzle key for frag reads

    // Q B-frags: lane holds Q[qrow][ks*32 + qd*8 + j]
    bf16x8 qf[2];
    {
        const bf16* qp = qkv + (size_t)qrow * LD_QKV + h * 64;
        qf[0] = *(const bf16x8*)(qp + qd * 8);
        qf[1] = *(const bf16x8*)(qp + 32 + qd * 8);
    }

    f32x4 O[4] = {};                   // O^T: D[row=d=dt*16+qd*4+r][col=q=c]
    float m_i = -1e30f, l_i = 0.f;
    const int nkb = (qb >> 1) + 1;     // 128-key chunks

    for (int kb = 0; kb < nkb; kb++) {
        __syncthreads();               // prior iteration's LDS reads done
#pragma unroll
        for (int ii = 0; ii < 4; ii++) {
            const int i = ii * 256 + threadIdx.x;
            const int kr = i >> 3, ch = i & 7;    // K: 128 rows x 8 chunks
            *(bf16x8*)&Ks[kr][(ch ^ (kr & 7)) * 8] =
                *(const bf16x8*)(qkv + (size_t)(kb * 128 + kr) * LD_QKV + C_DIM + h * 64 + ch * 8);
            const int vr = i >> 4, vch = i & 15;  // VT: 64 rows x 16 chunks
            *(bf16x8*)&VTs[vr][(vch ^ (vr & 7)) * 8] =
                *(const bf16x8*)(VT + ((size_t)h * 64 + vr) * T_SEQ + kb * 128 + vch * 8);
        }
        __syncthreads();

        // ---- S^T = K Q^T : rows = keys (kt*16 + qd*4 + r), cols = q (c) ----
        f32x4 ST[8];
#pragma unroll
        for (int kt = 0; kt < 8; kt++) {
            f32x4 z = {};
#pragma unroll
            for (int ks = 0; ks < 2; ks++) {
                bf16x8 kf = *(const bf16x8*)&Ks[kt * 16 + c][((ks * 4 + qd) ^ sw) * 8];
                z = __builtin_amdgcn_mfma_f32_16x16x32_bf16(kf, qf[ks], z, 0, 0, 0);
            }
            ST[kt] = z;
        }

        // ---- scale (+ causal mask only on the diagonal chunk) ----
        if (kb == nkb - 1) {
#pragma unroll
            for (int kt = 0; kt < 8; kt++)
#pragma unroll
                for (int r = 0; r < 4; r++) {
                    float s = ST[kt][r] * 0.125f;
                    if (kb * 128 + kt * 16 + qd * 4 + r > qrow) s = -1e30f;
                    ST[kt][r] = s;
                }
        } else {
#pragma unroll
            for (int kt = 0; kt < 8; kt++)
#pragma unroll
                for (int r = 0; r < 4; r++) ST[kt][r] *= 0.125f;
        }

        // ---- online softmax: per-lane scalar stats (q = qrow) ----
        float mb = -1e30f;
#pragma unroll
        for (int kt = 0; kt < 8; kt++)
#pragma unroll
            for (int r = 0; r < 4; r++) mb = fmaxf(mb, ST[kt][r]);
        mb = fmaxf(mb, __shfl_xor(mb, 16));
        mb = fmaxf(mb, __shfl_xor(mb, 32));
        const float mnew = fmaxf(m_i, mb);
        const float alpha = __expf(m_i - mnew);
        m_i = mnew;
        float rs = 0.f;
#pragma unroll
        for (int kt = 0; kt < 8; kt++)
#pragma unroll
            for (int r = 0; r < 4; r++) {
                const float p = __expf(ST[kt][r] - mnew);
                ST[kt][r] = p;
                rs += p;
            }
        rs += __shfl_xor(rs, 16);
        rs += __shfl_xor(rs, 32);
        l_i = l_i * alpha + rs;
#pragma unroll
        for (int dt = 0; dt < 4; dt++)
#pragma unroll
            for (int r = 0; r < 4; r++) O[dt][r] *= alpha;

        // ---- P^T -> Ps[q][key] via 8B vector writes (wave-private) ----
#pragma unroll
        for (int kt = 0; kt < 8; kt++) {
            bf16x4 pv;
#pragma unroll
            for (int r = 0; r < 4; r++) pv[r] = (bf16r)ST[kt][r];
            const int phys = (kt * 2 + (qd >> 1)) ^ sw;  // 16B-chunk swizzle
            *(bf16x4*)&Ps[w][c][phys * 8 + (qd & 1) * 4] = pv;
        }

        // ---- O^T += VT P^T ----
#pragma unroll
        for (int ks = 0; ks < 4; ks++) {
            bf16x8 pf = *(const bf16x8*)&Ps[w][c][((ks * 4 + qd) ^ sw) * 8];
#pragma unroll
            for (int dt = 0; dt < 4; dt++) {
                bf16x8 vf = *(const bf16x8*)&VTs[dt * 16 + c][((ks * 4 + qd) ^ sw) * 8];
                O[dt] = __builtin_amdgcn_mfma_f32_16x16x32_bf16(vf, pf, O[dt], 0, 0, 0);
            }
        }
    }

    // ---- epilogue: y[qrow][h*64 + d], 8B vector stores ----
    const float inv_l = 1.0f / l_i;
#pragma unroll
    for (int dt = 0; dt < 4; dt++) {
        bf16x4 ov;
#pragma unroll
        for (int r = 0; r < 4; r++) ov[r] = (bf16r)(O[dt][r] * inv_l);
        *(bf16x4*)(y + (size_t)qrow * C_DIM + h * 64 + dt * 16 + qd * 4) = ov;
    }
}

// ---------------------------------------------------------------------------
// launch.  Inputs f32, output f32.  ws peak = 56 MiB (same as round 8).
// ---------------------------------------------------------------------------
extern "C" void kernel_launch(void* const* d_in, const int* in_sizes, int n_in,
                              void* d_out, int out_size, void* d_ws, size_t ws_size,
                              hipStream_t stream) {
    const float* x        = (const float*)d_in[0];
    const float* attn_w   = (const float*)d_in[1];
    const float* ffn_w    = (const float*)d_in[2];
    const float* c_attn_w = (const float*)d_in[3];
    const float* c_proj_w = (const float*)d_in[4];
    const float* w1       = (const float*)d_in[5];
    const float* w2       = (const float*)d_in[6];
    const float* w3       = (const float*)d_in[7];
    float* xmid = (float*)d_out;

    char* ws = (char*)d_ws;
    bf16* cwA = (bf16*)(ws);
    bf16* cwP = (bf16*)(ws + MB(6));
    bf16* rms = (bf16*)(ws + MB(8));
    bf16* qkv = (bf16*)(ws + MB(16));
    bf16* VT  = (bf16*)(ws + MB(40));
    bf16* y   = (bf16*)(ws + MB(48));
    bf16* w1h = (bf16*)(ws + MB(16));
    bf16* w3h = (bf16*)(ws + MB(20));
    bf16* w2h = (bf16*)(ws + MB(24));
    bf16* h1h = (bf16*)(ws + MB(28));

    // 1. attention weights -> bf16
    cvt_w<<<512, 256, 0, stream>>>(c_attn_w, 0, (ushort4*)cwA, 3072 * 1024 / 4);
    cvt_w<<<512, 256, 0, stream>>>(c_proj_w, 0, (ushort4*)cwP, 1024 * 1024 / 4);
    // 2. rms1 = rmsnorm(x, attn_norm_w)
    rmsnorm_k<<<T_SEQ, 256, 0, stream>>>(x, attn_w, rms);
    // 3. qkv = rms1 @ c_attn^T   [4096, 3072]
    gemm128<0, 0><<<dim3(24, 32), 256, 0, stream>>>(rms, C_DIM, cwA, C_DIM, nullptr, qkv, 3072, 1024);
    // 4. VT (V transposed per head) + MFMA flash attention v2
    build_tr<<<dim3(64, 16), 256, 0, stream>>>(qkv, VT, 2 * C_DIM);
    attn_mfma<<<1024, 256, 0, stream>>>(qkv, VT, y);
    // 5. xmid = x + y @ c_proj^T   (f32, into d_out)
    gemm128<2, 1><<<dim3(8, 32), 256, 0, stream>>>(y, C_DIM, cwP, C_DIM, x, xmid, 1024, 1024);
    // 6. rms2 = rmsnorm(xmid, ffn_norm_w)
    rmsnorm_k<<<T_SEQ, 256, 0, stream>>>(xmid, ffn_w, rms);
    // 7. FFN in two Hf=2048 halves; w2-partials accumulate into xmid in place.
    for (int hh = 0; hh < 2; hh++) {
        cvt_w<<<512, 256, 0, stream>>>(w1, (size_t)hh * 2048 * 1024, (ushort4*)w1h, 2048 * 1024 / 4);
        gemm128<0, 0><<<dim3(16, 32), 256, 0, stream>>>(rms, C_DIM, w1h, C_DIM, nullptr, h1h, 2048, 1024);
        cvt_w<<<512, 256, 0, stream>>>(w3, (size_t)hh * 2048 * 1024, (ushort4*)w3h, 2048 * 1024 / 4);
        gemm128<3, 0><<<dim3(16, 32), 256, 0, stream>>>(rms, C_DIM, w3h, C_DIM, h1h, h1h, 2048, 1024);
        cvt_w2h<<<2048, 256, 0, stream>>>(w2, hh * 2048, (ushort4*)w2h);
        gemm128<2, 1><<<dim3(8, 32), 256, 0, stream>>>(h1h, 2048, w2h, 2048, xmid, xmid, 1024, 2048);
    }
}